// Round 2
// 326.982 us; speedup vs baseline: 1.0305x; 1.0305x over previous
//
#include <hip/hip_runtime.h>
#include <math.h>

#define BATCH 2
#define SEQ   2048
#define NH    64
#define HD    64
#define DS    128
#define CS    256
#define NC    8   // SEQ/CS
#define LOG2E 1.4426950408889634f

typedef __attribute__((ext_vector_type(8))) short s16x8;   // 8 bf16 (4 VGPR)
typedef __attribute__((ext_vector_type(4))) float f32x4;   // 16x16 acc

#define MFMA16(a,b,c) __builtin_amdgcn_mfma_f32_16x16x32_bf16(a, b, c, 0, 0, 0)

// HW packed f32->bf16 (RNE), one VOP3 instead of ~9 VALU ops
__device__ inline unsigned cvt_pk_bf16(float a, float b) {
    unsigned r;
    asm("v_cvt_pk_bf16_f32 %0, %1, %2" : "=v"(r) : "v"(a), "v"(b));
    return r;
}
// raw 2^x.  All dacs values are pre-scaled by log2(e).
__device__ inline float exp2f_fast(float x) {
#if __has_builtin(__builtin_amdgcn_exp2f)
    return __builtin_amdgcn_exp2f(x);
#else
    float r;
    asm("v_exp_f32 %0, %1" : "=v"(r) : "v"(x));
    return r;
#endif
}
__device__ inline float2 unpack2bf(unsigned u) {
    return make_float2(__uint_as_float(u << 16), __uint_as_float(u & 0xffff0000u));
}

union frag_u { unsigned u[4]; s16x8 v; };

// ---------------------------------------------------------------------------
// K1: dt softplus + dA cumsum (fp32).  dtp/dacs: ((b*NH+h)*NC+c)*CS + s
// dacs is written PRE-SCALED by log2(e): every consumer only exponentiates it.
// ---------------------------------------------------------------------------
__global__ __launch_bounds__(CS) void k1_dt(
    const float* __restrict__ dt, const float* __restrict__ A,
    const float* __restrict__ dt_bias,
    float* __restrict__ dtp, float* __restrict__ dacs)
{
    int bid = blockIdx.x;                 // ((b*NH+h)*NC+c)
    int c = bid % NC;
    int h = (bid / NC) % NH;
    int b = bid / (NC * NH);
    int s = threadIdx.x;

    float v  = dt[((size_t)b * SEQ + c * CS + s) * NH + h] + dt_bias[h];
    float sp = fmaxf(v, 0.f) + log1pf(__expf(-fabsf(v)));
    float dA = sp * (A[h] * LOG2E);       // log2-domain

    __shared__ float sm[CS];
    sm[s] = dA;
    __syncthreads();
    for (int off = 1; off < CS; off <<= 1) {
        float tt = (s >= off) ? sm[s - off] : 0.f;
        __syncthreads();
        sm[s] += tt;
        __syncthreads();
    }
    size_t o = (size_t)bid * CS + s;
    dtp[o]  = sp;
    dacs[o] = sm[s];
}

// ---------------------------------------------------------------------------
// K0a: xdt[(b,c,h), p, s] = bf16( x[b,s,h,p] * dtp[s] ).  1024 blocks.
// ---------------------------------------------------------------------------
__global__ __launch_bounds__(256) void k0a_xdt(
    const float* __restrict__ x, const float* __restrict__ dtp,
    unsigned* __restrict__ xdt)
{
    int bid = blockIdx.x;             // ((b*NC+c)*NH+h)
    int h = bid & 63, c = (bid >> 6) & 7, b = bid >> 9;
    int t = threadIdx.x;
    size_t dt_base = ((size_t)(b*NH + h)*NC + c)*CS;
    __shared__ float tile[64][65];
    __shared__ float dtS[64];
    for (int st = 0; st < 4; ++st) {
        int s0 = st * 64;
        __syncthreads();
        if (t < 64) dtS[t] = dtp[dt_base + s0 + t];
        #pragma unroll
        for (int i = 0; i < 16; ++i) {
            int f = t + i * 256;
            int row = f >> 6, col = f & 63;
            tile[row][col] = x[((size_t)(b*SEQ + c*CS + s0 + row)*NH + h)*HD + col];
        }
        __syncthreads();
        #pragma unroll
        for (int i = 0; i < 8; ++i) {
            int f = t + i * 256;
            int p = f >> 5, sd = f & 31;
            xdt[((size_t)bid*64 + p)*128 + (s0 >> 1) + sd] =
                cvt_pk_bf16(tile[2*sd][p] * dtS[2*sd], tile[2*sd+1][p] * dtS[2*sd+1]);
        }
    }
}

// ---------------------------------------------------------------------------
// K0b: flat f32 -> packed bf16 cast (for C). 256 blocks x 256 thr x 8 elems.
// ---------------------------------------------------------------------------
__global__ __launch_bounds__(256) void k0b_cast(
    const float* __restrict__ src, unsigned* __restrict__ dst)
{
    size_t f = (size_t)blockIdx.x * 256 + threadIdx.x;
    const float4* s4 = (const float4*)(src + f * 8);
    float4 a = s4[0], bq = s4[1];
    uint4 o;
    o.x = cvt_pk_bf16(a.x,  a.y);  o.y = cvt_pk_bf16(a.z,  a.w);
    o.z = cvt_pk_bf16(bq.x, bq.y); o.w = cvt_pk_bf16(bq.z, bq.w);
    *(uint4*)(dst + f * 4) = o;
}

// ---------------------------------------------------------------------------
// K0c: B[b,s,n] f32 -> BT[(b,c), n, s] bf16. 128 blocks (bc*8 + nt*4 + st).
// ---------------------------------------------------------------------------
__global__ __launch_bounds__(256) void k0c_BT(
    const float* __restrict__ Bg, unsigned* __restrict__ BT)
{
    int bid = blockIdx.x;
    int st = bid & 3, nt = (bid >> 2) & 1, bc = bid >> 3;
    int b = bc >> 3, c = bc & 7;
    int s0 = st * 64, n0 = nt * 64;
    int t = threadIdx.x;
    __shared__ float tile[64][65];
    #pragma unroll
    for (int i = 0; i < 16; ++i) {
        int f = t + i * 256;
        int row = f >> 6, col = f & 63;
        tile[row][col] = Bg[(size_t)(b*SEQ + c*CS + s0 + row)*DS + n0 + col];
    }
    __syncthreads();
    #pragma unroll
    for (int i = 0; i < 8; ++i) {
        int f = t + i * 256;
        int n = f >> 5, sd = f & 31;
        BT[((size_t)bc*128 + n0 + n)*128 + (s0 >> 1) + sd] =
            cvt_pk_bf16(tile[2*sd][n], tile[2*sd+1][n]);
    }
}

// ---------------------------------------------------------------------------
// K2: CB tiles (fp32 VALU compute, bf16 packed output). Only tl >= ts tiles.
// grid = B*NC*10.
// ---------------------------------------------------------------------------
__global__ __launch_bounds__(256) void k2_cb(
    const float* __restrict__ Bg_, const float* __restrict__ Cg_,
    unsigned* __restrict__ cb_bf)
{
    const int TLt[10] = {0,1,1,2,2,2,3,3,3,3};
    const int TSt[10] = {0,0,1,0,1,2,0,1,2,3};
    int bid = blockIdx.x;
    int ti = bid % 10;
    int bc = bid / 10;
    int tl = TLt[ti], ts = TSt[ti];
    int b = bc / NC, c = bc % NC;

    const float* Cg = Cg_ + (size_t)(b * SEQ + c * CS + tl * 64) * DS;
    const float* Bg = Bg_ + (size_t)(b * SEQ + c * CS + ts * 64) * DS;

    __shared__ __align__(16) float Ct[32][68];
    __shared__ __align__(16) float Bt[32][68];

    int t  = threadIdx.x;
    int tx = t & 15, ty = t >> 4;
    int s0 = tx * 4, l0 = ty * 4;
    float acc[4][4] = {};

    for (int n0 = 0; n0 < DS; n0 += 32) {
        __syncthreads();
        {
            int r  = t >> 5;
            int nn = t & 31;
            #pragma unroll
            for (int i = 0; i < 8; ++i) {
                Ct[nn][r + i * 8] = Cg[(size_t)(r + i * 8) * DS + n0 + nn];
                Bt[nn][r + i * 8] = Bg[(size_t)(r + i * 8) * DS + n0 + nn];
            }
        }
        __syncthreads();
        #pragma unroll 8
        for (int n = 0; n < 32; ++n) {
            float4 cv = *(const float4*)&Ct[n][l0];
            float4 bv = *(const float4*)&Bt[n][s0];
            float cva[4] = {cv.x, cv.y, cv.z, cv.w};
            float bva[4] = {bv.x, bv.y, bv.z, bv.w};
            #pragma unroll
            for (int i = 0; i < 4; ++i)
                #pragma unroll
                for (int j = 0; j < 4; ++j)
                    acc[i][j] += cva[i] * bva[j];
        }
    }

    unsigned* cbg = cb_bf + (size_t)bc * 32768;   // 256*128 dwords
    #pragma unroll
    for (int i = 0; i < 4; ++i) {
        int row  = tl * 64 + l0 + i;
        int colb = (ts * 64 + s0) >> 1;
        uint2 wv;
        wv.x = cvt_pk_bf16(acc[i][0], acc[i][1]);
        wv.y = cvt_pk_bf16(acc[i][2], acc[i][3]);
        *(uint2*)&cbg[(size_t)row * 128 + colb] = wv;
    }
}

// ---------------------------------------------------------------------------
// K3: chunk_state, fragment-direct. grid = B*NC*NH, 4 waves; wave w owns
// p-tile w. A = xdt * exp(daL - dacs[s]) computed in registers; B = BT direct.
// Output states_bf[(b,c,h)][p][n] bf16.
// ---------------------------------------------------------------------------
__global__ __launch_bounds__(256) void k3_chunk_state(
    const unsigned* __restrict__ xdt, const unsigned* __restrict__ BT,
    const float* __restrict__ dacs, unsigned short* __restrict__ states_bf)
{
    int bid = blockIdx.x;                 // ((b*NC+c)*NH+h)
    int bc = bid >> 6;
    int h = bid & 63, c = (bid >> 6) & 7, b = bid >> 9;
    int t = threadIdx.x;
    int w = t >> 6, lane = t & 63, m16 = lane & 15, q = lane >> 4;

    size_t dt_base = ((size_t)(b*NH + h)*NC + c)*CS;
    __shared__ float coS[CS];
    {
        float daL = dacs[dt_base + CS - 1];
        coS[t] = exp2f_fast(daL - dacs[dt_base + t]);
    }
    __syncthreads();

    const unsigned* xb = xdt + (size_t)bid * 8192;
    const unsigned* bb = BT + (size_t)bc * 16384;

    f32x4 acc[8] = {};

    #pragma unroll
    for (int ks = 0; ks < 4; ++ks) {
        #pragma unroll
        for (int kk = 0; kk < 2; ++kk) {
            int kd = ks*32 + kk*16 + q*4;
            int sbase = ks*64 + kk*32 + q*8;
            uint4 xq = *(const uint4*)&xb[(w*16 + m16)*128 + kd];
            float co8[8];
            *(float4*)&co8[0] = *(const float4*)&coS[sbase];
            *(float4*)&co8[4] = *(const float4*)&coS[sbase + 4];
            frag_u af;
            {
                float2 v0 = unpack2bf(xq.x), v1 = unpack2bf(xq.y);
                float2 v2 = unpack2bf(xq.z), v3 = unpack2bf(xq.w);
                af.u[0] = cvt_pk_bf16(v0.x*co8[0], v0.y*co8[1]);
                af.u[1] = cvt_pk_bf16(v1.x*co8[2], v1.y*co8[3]);
                af.u[2] = cvt_pk_bf16(v2.x*co8[4], v2.y*co8[5]);
                af.u[3] = cvt_pk_bf16(v3.x*co8[6], v3.y*co8[7]);
            }
            #pragma unroll
            for (int nt = 0; nt < 8; ++nt) {
                s16x8 bf8 = *(const s16x8*)&bb[(nt*16 + m16)*128 + kd];
                acc[nt] = MFMA16(af.v, bf8, acc[nt]);
            }
        }
    }

    unsigned short* sg = states_bf + (size_t)bid * 8192;
    #pragma unroll
    for (int nt = 0; nt < 8; ++nt) {
        #pragma unroll
        for (int r = 0; r < 4; r += 2) {
            int p = w*16 + q*4 + r;
            unsigned u = cvt_pk_bf16(acc[nt][r], acc[nt][r+1]);
            sg[p*128 + nt*16 + m16]     = (unsigned short)u;
            sg[(p+1)*128 + nt*16 + m16] = (unsigned short)(u >> 16);
        }
    }
}

// ---------------------------------------------------------------------------
// K4: state_passing. Reads states_bf (as dword pairs), fp32 recurrence across
// chunks, writes prevT bf16 pairs + final_states fp32.
// ---------------------------------------------------------------------------
__global__ __launch_bounds__(256) void k4_state_passing(
    const unsigned* __restrict__ states_bf, const float* __restrict__ dacs,
    unsigned* __restrict__ prevT, float* __restrict__ final_states)
{
    int e = blockIdx.x * 256 + threadIdx.x;   // over B*NH*HD*DS/2 = 524288
    int n2 = e & 63;
    int p  = (e >> 6) & 63;
    int h  = (e >> 12) & 63;
    int b  = e >> 18;

    float r0 = 0.f, r1 = 0.f;
    #pragma unroll
    for (int c = 0; c < NC; ++c) {
        size_t idx = (((size_t)(b*NC + c)*NH + h)*HD + p)*64 + n2;
        float2 vv = unpack2bf(states_bf[idx]);
        prevT[idx] = cvt_pk_bf16(r0, r1);
        float el = exp2f_fast(dacs[((size_t)(b*NH + h)*NC + c)*CS + CS - 1]);
        r0 = el * r0 + vv.x;
        r1 = el * r1 + vv.y;
    }
    float* fg = final_states + (((size_t)(b*NH + h)*HD + p)*DS + 2*n2);
    fg[0] = r0; fg[1] = r1;
}

// ---------------------------------------------------------------------------
// K5: chunk_scan, fragment-direct, no mid-kernel barriers. grid = B*NC*NH,
// 4 waves. Wave w owns interleaved 16-row l-tiles {w, w+4, w+8, w+12}
// (balanced triangle). Phase B: A = cb*decay masked in regs (cb global,
// shared across h -> L2); B = xdt direct. Phase A: A = Cb*exp(dacs[l]),
// B = prevT direct; shared accumulator. Epilogue fused.
// ---------------------------------------------------------------------------
__global__ __launch_bounds__(256) void k5_chunk_scan(
    const float* __restrict__ x, const float* __restrict__ z,
    const unsigned* __restrict__ Cb, const float* __restrict__ Dp,
    const float* __restrict__ dacs, const unsigned* __restrict__ cb_bf,
    const unsigned* __restrict__ xdt, const unsigned* __restrict__ prevT,
    float* __restrict__ out)
{
    int bid = blockIdx.x;                 // ((b*NC+c)*NH+h)
    int h = bid & 63, c = (bid >> 6) & 7, b = bid >> 9;
    int bc = bid >> 6;
    int t = threadIdx.x;
    int w = t >> 6, lane = t & 63, m16 = lane & 15, q = lane >> 4;

    __shared__ float dacsS[CS];
    __shared__ float elS[CS];
    size_t dt_base = ((size_t)(b*NH + h)*NC + c)*CS;
    {
        float dv = dacs[dt_base + t];     // log2-domain
        dacsS[t] = dv;
        elS[t]   = exp2f_fast(dv);
    }
    __syncthreads();

    const unsigned* xb  = xdt + (size_t)bid * 8192;
    const unsigned* cbb = cb_bf + (size_t)bc * 32768;

    f32x4 acc[4][4] = {};                 // [jj][pt]; l-tile jj -> rows (w+4jj)*16
    float dlv[4];
    #pragma unroll
    for (int jj = 0; jj < 4; ++jj) dlv[jj] = dacsS[(w + 4*jj)*16 + m16];

    // ---- phase B: intra-chunk masked scan ----
    #pragma unroll
    for (int st = 0; st < 4; ++st) {
        int s0 = st * 64;
        #pragma unroll
        for (int kk = 0; kk < 2; ++kk) {
            int kd = (s0 >> 1) + kk*16 + q*4;
            s16x8 bfr[4];
            #pragma unroll
            for (int pt = 0; pt < 4; ++pt)
                bfr[pt] = *(const s16x8*)&xb[(pt*16 + m16)*128 + kd];
            int sbase = s0 + kk*32 + q*8;
            float ds8[8];
            *(float4*)&ds8[0] = *(const float4*)&dacsS[sbase];
            *(float4*)&ds8[4] = *(const float4*)&dacsS[sbase + 4];
            #pragma unroll
            for (int jj = st; jj < 4; ++jj) {
                // diagonal fully-masked sub-tile for wave 0:
                if (st == jj && kk == 1 && w == 0) continue;
                int lrow = (w + 4*jj)*16 + m16;    // chunk-local l
                float dl = dlv[jj];
                uint4 cbq = *(const uint4*)&cbb[(size_t)lrow*128 + kd];
                frag_u af;
                float2 v0 = unpack2bf(cbq.x), v1 = unpack2bf(cbq.y);
                float2 v2 = unpack2bf(cbq.z), v3 = unpack2bf(cbq.w);
                float wv[8];
                wv[0] = v0.x * exp2f_fast(dl - ds8[0]);
                wv[1] = v0.y * exp2f_fast(dl - ds8[1]);
                wv[2] = v1.x * exp2f_fast(dl - ds8[2]);
                wv[3] = v1.y * exp2f_fast(dl - ds8[3]);
                wv[4] = v2.x * exp2f_fast(dl - ds8[4]);
                wv[5] = v2.y * exp2f_fast(dl - ds8[5]);
                wv[6] = v3.x * exp2f_fast(dl - ds8[6]);
                wv[7] = v3.y * exp2f_fast(dl - ds8[7]);
                if (st == jj) {                    // diagonal: apply causal mask
                    #pragma unroll
                    for (int j = 0; j < 8; ++j)
                        wv[j] = (sbase + j <= lrow) ? wv[j] : 0.f;
                }
                af.u[0] = cvt_pk_bf16(wv[0], wv[1]);
                af.u[1] = cvt_pk_bf16(wv[2], wv[3]);
                af.u[2] = cvt_pk_bf16(wv[4], wv[5]);
                af.u[3] = cvt_pk_bf16(wv[6], wv[7]);
                #pragma unroll
                for (int pt = 0; pt < 4; ++pt)
                    acc[jj][pt] = MFMA16(af.v, bfr[pt], acc[jj][pt]);
            }
        }
    }

    // ---- phase A: inter-chunk term, decay folded into C-fragment ----
    {
        const unsigned* pb = prevT + (size_t)bid * 4096;
        float elv[4];
        #pragma unroll
        for (int jj = 0; jj < 4; ++jj) elv[jj] = elS[(w + 4*jj)*16 + m16];
        #pragma unroll
        for (int kq = 0; kq < 4; ++kq) {
            int kd = kq*16 + q*4;
            s16x8 pfr[4];
            #pragma unroll
            for (int pt = 0; pt < 4; ++pt)
                pfr[pt] = *(const s16x8*)&pb[(pt*16 + m16)*64 + kd];
            #pragma unroll
            for (int jj = 0; jj < 4; ++jj) {
                int lrow = (w + 4*jj)*16 + m16;
                uint4 cq = *(const uint4*)&Cb[(size_t)(b*SEQ + c*CS + lrow)*64 + kd];
                float el = elv[jj];
                frag_u af;
                float2 v0 = unpack2bf(cq.x), v1 = unpack2bf(cq.y);
                float2 v2 = unpack2bf(cq.z), v3 = unpack2bf(cq.w);
                af.u[0] = cvt_pk_bf16(v0.x*el, v0.y*el);
                af.u[1] = cvt_pk_bf16(v1.x*el, v1.y*el);
                af.u[2] = cvt_pk_bf16(v2.x*el, v2.y*el);
                af.u[3] = cvt_pk_bf16(v3.x*el, v3.y*el);
                #pragma unroll
                for (int pt = 0; pt < 4; ++pt)
                    acc[jj][pt] = MFMA16(af.v, pfr[pt], acc[jj][pt]);
            }
        }
    }

    // ---- epilogue: + x*D, SiLU(z) gate ----
    float Dh = Dp[h];
    #pragma unroll
    for (int jj = 0; jj < 4; ++jj) {
        #pragma unroll
        for (int r = 0; r < 4; ++r) {
            int l = (w + 4*jj)*16 + q*4 + r;
            size_t gro = ((size_t)(b*SEQ + c*CS + l)*NH + h)*HD;
            #pragma unroll
            for (int pt = 0; pt < 4; ++pt) {
                int p = pt*16 + m16;
                float xv = x[gro + p], zv = z[gro + p];
                float o = acc[jj][pt][r] + xv * Dh;
                float sig = 1.f / (1.f + __expf(-zv));
                out[gro + p] = o * (zv * sig);
            }
        }
    }
}

// ---------------------------------------------------------------------------
extern "C" void kernel_launch(void* const* d_in, const int* in_sizes, int n_in,
                              void* d_out, int out_size, void* d_ws, size_t ws_size,
                              hipStream_t stream)
{
    (void)in_sizes; (void)n_in; (void)out_size; (void)ws_size;
    const float* x       = (const float*)d_in[0];
    const float* dt      = (const float*)d_in[1];
    const float* A       = (const float*)d_in[2];
    const float* B       = (const float*)d_in[3];
    const float* C       = (const float*)d_in[4];
    const float* D       = (const float*)d_in[5];
    const float* z       = (const float*)d_in[6];
    const float* dt_bias = (const float*)d_in[7];

    float* out           = (float*)d_out;
    float* final_states  = out + (size_t)BATCH * SEQ * NH * HD;

    float* ws        = (float*)d_ws;
    float* dtp       = ws;                                   // 262144 f
    float* dacs      = dtp + 262144;                         // 262144 f
    unsigned short* states_bf = (unsigned short*)(dacs + 262144); // 8388608 u16 = 4194304 dw
    unsigned* prevT  = (unsigned*)(states_bf + 8388608);     // 4194304 dw
    unsigned* cb_bf  = prevT + 4194304;                      // 524288 dw
    unsigned* xdt    = cb_bf + 524288;                       // 8388608 dw
    unsigned* BT     = xdt + 8388608;                        // 262144 dw
    unsigned* Cb     = BT + 262144;                          // 262144 dw
    // total: 18,350,080 dwords = 73.4 MB

    k1_dt   <<<BATCH * NH * NC, CS,  0, stream>>>(dt, A, dt_bias, dtp, dacs);
    k0a_xdt <<<BATCH * NC * NH, 256, 0, stream>>>(x, dtp, xdt);
    k0b_cast<<<256,             256, 0, stream>>>(C, Cb);
    k0c_BT  <<<BATCH * NC * 8,  256, 0, stream>>>(B, BT);
    k2_cb   <<<BATCH * NC * 10, 256, 0, stream>>>(B, C, cb_bf);
    k3_chunk_state<<<BATCH * NC * NH, 256, 0, stream>>>(xdt, BT, dacs, states_bf);
    k4_state_passing<<<(BATCH * NH * HD * DS / 2) / 256, 256, 0, stream>>>(
        (const unsigned*)states_bf, dacs, prevT, final_states);
    k5_chunk_scan<<<BATCH * NC * NH, 256, 0, stream>>>(x, z, Cb, D, dacs,
                                                       cb_bf, xdt, prevT, out);
}